// Round 5
// baseline (139.561 us; speedup 1.0000x reference)
//
#include <hip/hip_runtime.h>
#include <hip/hip_bf16.h>
#include <math.h>

#define SIM_THR 0.8f
// sqrt(2 * log2(e)): folds the x2 temperature and the exp->exp2 conversion into the data
#define LAT_SCALE 1.6986436f
#define LN2 0.6931471805599453f

typedef __attribute__((ext_vector_type(8))) short short8v;   // 8 bf16
typedef __attribute__((ext_vector_type(4))) float f32x4;
typedef __attribute__((ext_vector_type(4))) _Float16 half4v; // 4 f16

__device__ __forceinline__ void glds16(const void* g, void* l) {
    __builtin_amdgcn_global_load_lds(
        (const __attribute__((address_space(1))) void*)g,
        (__attribute__((address_space(3))) void*)l, 16, 0, 0);
}

__device__ __forceinline__ float fexp2(float x) {
#if __has_builtin(__builtin_amdgcn_exp2f)
    return __builtin_amdgcn_exp2f(x);
#else
    return exp2f(x);
#endif
}

// ---------------- kernel 1: L2-normalize latent rows -> bf16 (scaled) ----------------
__global__ __launch_bounds__(256) void k_norm_lat(const float* __restrict__ in,
                                                  __hip_bfloat16* __restrict__ out, int B) {
    int row = blockIdx.x * 4 + (threadIdx.x >> 6);
    int lane = threadIdx.x & 63;
    if (row >= B) return;
    float2 v = reinterpret_cast<const float2*>(in + (size_t)row * 128)[lane];
    float ss = v.x * v.x + v.y * v.y;
#pragma unroll
    for (int m = 1; m < 64; m <<= 1) ss += __shfl_xor(ss, m);
    float sc = LAT_SCALE / fmaxf(sqrtf(ss), 1e-12f);
    __hip_bfloat162 o;
    o.x = __float2bfloat16(v.x * sc);
    o.y = __float2bfloat16(v.y * sc);
    reinterpret_cast<__hip_bfloat162*>(out + (size_t)row * 128)[lane] = o;
}

// ---------------- kernel 2: L2-normalize abr rows -> f16, K padded to 16 ----------------
__global__ __launch_bounds__(256) void k_norm_abr(const float* __restrict__ in,
                                                  _Float16* __restrict__ out, int B) {
    int row = blockIdx.x * 256 + threadIdx.x;
    if (row >= B) return;
    float v[6];
    float ss = 0.f;
#pragma unroll
    for (int d = 0; d < 6; ++d) { v[d] = in[(size_t)row * 6 + d]; ss += v[d] * v[d]; }
    float sc = 1.0f / fmaxf(sqrtf(ss), 1e-12f);
#pragma unroll
    for (int d = 0; d < 6; ++d) out[(size_t)row * 16 + d] = (_Float16)(v[d] * sc);
#pragma unroll
    for (int d = 6; d < 16; ++d) out[(size_t)row * 16 + d] = (_Float16)0.f;
}

// ---------------- merged epilogue: abr MFMA + fused per-element stats ----------------
template <bool DIAG>
__device__ __forceinline__ void epilogue(const half4v (&aa)[4], const half4v (&bb)[4],
                                         const f32x4 (&acc)[4][4],
                                         float (&esum_r)[4][4], float (&sumd_r)[4][4],
                                         float (&cnt_r)[4][4], float (&sumsim_r)[4][4],
                                         int lr, int lg, int wr, int wc) {
#pragma unroll
    for (int m = 0; m < 4; ++m) {
#pragma unroll
        for (int n = 0; n < 4; ++n) {
#if __has_builtin(__builtin_amdgcn_mfma_f32_16x16x16f16)
            f32x4 aacc = __builtin_amdgcn_mfma_f32_16x16x16f16(
                aa[m], bb[n], (f32x4){0.f, 0.f, 0.f, 0.f}, 0, 0, 0);
#else
            f32x4 aacc;
#pragma unroll
            for (int r = 0; r < 4; ++r) {
                float s = 0.f;
#pragma unroll
                for (int k = 0; k < 4; ++k)
                    s += (float)aa[m][k] * (float)bb[n][k];  // unreachable placeholder
                aacc[r] = s;
            }
#endif
#pragma unroll
            for (int r = 0; r < 4; ++r) {
                float d = acc[m][n][r];       // = s_ij * log2(e)
                float sim = aacc[r];
                float e = fexp2(d);
                bool pred = sim > SIM_THR;
                if (DIAG) {
                    // row_l == col_l  <=>  wr*64+m*16+lg*4+r == wc*64+n*16+lr
                    bool dg = (wr * 64 + m * 16 + lg * 4 + r) == (wc * 64 + n * 16 + lr);
                    if (dg) { e = 0.f; pred = false; }
                }
                float p = pred ? 1.f : 0.f;
                esum_r[m][r] += e;
                cnt_r[m][r] += p;
                sumsim_r[m][r] = fmaf(p, sim, sumsim_r[m][r]);
                sumd_r[m][r] = fmaf(p, d, sumd_r[m][r]);
            }
        }
    }
}

// ---------------- fused sweep ----------------
// Block (jc, bi): rows [bi*128,+128), sweeps 8 j-tiles of 128. Per row accumulates
// (esum, sum_d_pos, cnt, sum_sim); one float4 slab write per (row, wc). No atomics.
__global__ __launch_bounds__(256, 2) void k_sweep(
    const __hip_bfloat16* __restrict__ lnbf,
    const _Float16* __restrict__ abrf,
    float4* __restrict__ slab, int B)
{
    extern __shared__ char lds[];
    __hip_bfloat16* Alat = (__hip_bfloat16*)lds;            // 32 KB
    __hip_bfloat16* Blat = (__hip_bfloat16*)(lds + 32768);  // 32 KB

    int jc = blockIdx.x, bi = blockIdx.y;
    int i0 = bi * 128;
    int tid = threadIdx.x;
    int w = tid >> 6, l = tid & 63;
    int lr = l & 15, lg = l >> 4;
    int wr = w >> 1, wc = w & 1;
    int lrow = l >> 4, lch = l & 15;

    // ---- prologue: stage A panel + B panel (tile 0); XOR-swizzled source ----
    {
        int j0 = jc * 1024;
#pragma unroll
        for (int c = 0; c < 8; ++c) {
            int rbase = w * 32 + c * 4;
            int row = rbase + lrow;
            int sch = lch ^ (row & 7);
            glds16(lnbf + (size_t)(i0 + row) * 128 + sch * 8, Alat + rbase * 128);
            glds16(lnbf + (size_t)(j0 + row) * 128 + sch * 8, Blat + rbase * 128);
        }
    }

    // ---- abr A fragments direct from global (L2-resident) ----
    half4v aa[4];
#pragma unroll
    for (int m = 0; m < 4; ++m)
        aa[m] = *reinterpret_cast<const half4v*>(
            abrf + (size_t)(i0 + wr * 64 + m * 16 + lr) * 16 + lg * 4);

    __syncthreads();

    // ---- A latent fragments: loop-invariant, hoist to registers once ----
    short8v afr[4][4];
#pragma unroll
    for (int kk = 0; kk < 4; ++kk) {
        int ch = (kk * 4 + lg) ^ (lr & 7);
#pragma unroll
        for (int m = 0; m < 4; ++m)
            afr[kk][m] = *reinterpret_cast<const short8v*>(
                Alat + (wr * 64 + m * 16 + lr) * 128 + ch * 8);
    }

    float esum_r[4][4] = {{0.f}}, sumd_r[4][4] = {{0.f}};
    float cnt_r[4][4] = {{0.f}}, sumsim_r[4][4] = {{0.f}};

#pragma unroll 1
    for (int t = 0; t < 8; ++t) {
        int jt = jc * 8 + t;
        bool dtile = (jt == bi);

        // abr B fragments direct from global
        half4v bb[4];
#pragma unroll
        for (int n = 0; n < 4; ++n)
            bb[n] = *reinterpret_cast<const half4v*>(
                abrf + (size_t)(jt * 128 + wc * 64 + n * 16 + lr) * 16 + lg * 4);

        // ---- latent MFMA ----
        f32x4 acc[4][4];
#pragma unroll
        for (int m = 0; m < 4; ++m)
#pragma unroll
            for (int n = 0; n < 4; ++n) acc[m][n] = (f32x4){0.f, 0.f, 0.f, 0.f};
#pragma unroll
        for (int kk = 0; kk < 4; ++kk) {
            int ch = (kk * 4 + lg) ^ (lr & 7);
            short8v b[4];
#pragma unroll
            for (int n = 0; n < 4; ++n)
                b[n] = *reinterpret_cast<const short8v*>(
                    Blat + (wc * 64 + n * 16 + lr) * 128 + ch * 8);
#pragma unroll
            for (int m = 0; m < 4; ++m)
#pragma unroll
                for (int n = 0; n < 4; ++n)
                    acc[m][n] = __builtin_amdgcn_mfma_f32_16x16x32_bf16(afr[kk][m], b[n], acc[m][n], 0, 0, 0);
        }
        __syncthreads();   // all Blat reads done -> reusable

        // ---- issue next B staging; flight hidden under epilogue ----
        if (t < 7) {
            int j0n = (jt + 1) * 128;
#pragma unroll
            for (int c = 0; c < 8; ++c) {
                int rbase = w * 32 + c * 4;
                int row = rbase + lrow;
                int sch = lch ^ (row & 7);
                glds16(lnbf + (size_t)(j0n + row) * 128 + sch * 8, Blat + rbase * 128);
            }
        }

        // ---- merged epilogue (registers only) ----
        if (dtile)
            epilogue<true>(aa, bb, acc, esum_r, sumd_r, cnt_r, sumsim_r, lr, lg, wr, wc);
        else
            epilogue<false>(aa, bb, acc, esum_r, sumd_r, cnt_r, sumsim_r, lr, lg, wr, wc);

        if (t < 7) __syncthreads();   // vmcnt drained -> next B ready
    }

    // ---- reduce over the 16 column-lanes and store one float4 per row ----
#pragma unroll
    for (int m = 0; m < 4; ++m)
#pragma unroll
        for (int r = 0; r < 4; ++r) {
            float a0 = esum_r[m][r], a1 = sumd_r[m][r], a2 = cnt_r[m][r], a3 = sumsim_r[m][r];
#pragma unroll
            for (int d2 = 1; d2 < 16; d2 <<= 1) {
                a0 += __shfl_xor(a0, d2);
                a1 += __shfl_xor(a1, d2);
                a2 += __shfl_xor(a2, d2);
                a3 += __shfl_xor(a3, d2);
            }
            if (lr == 0) {
                int row_g = i0 + wr * 64 + m * 16 + lg * 4 + r;
                slab[(size_t)(jc * 2 + wc) * B + row_g] = make_float4(a0, a1, a2, a3);
            }
        }
}

// ---------------- per-row finalize + block partials ----------------
__global__ __launch_bounds__(256) void k_rows(const float4* __restrict__ slab,
                                              float* __restrict__ pC, float* __restrict__ pSM,
                                              float* __restrict__ pLN, int B) {
    __shared__ float sc[4], sm[4], sl[4];
    int tid = threadIdx.x;
    int i = blockIdx.x * 256 + tid;
    float S = 0.f, sd = 0.f, c = 0.f, smm = 0.f;
#pragma unroll
    for (int k = 0; k < 16; ++k) {
        float4 v = slab[(size_t)k * B + i];
        S += v.x; sd += v.y; c += v.z; smm += v.w;
    }
    // loss row term: c*log(S) - sum_pos s;  sd holds sum_pos (s*log2e) -> *ln2
    float ln = (c > 0.f) ? c * logf(S) - LN2 * sd : 0.f;
#pragma unroll
    for (int d = 1; d < 64; d <<= 1) {
        c += __shfl_xor(c, d); smm += __shfl_xor(smm, d); ln += __shfl_xor(ln, d);
    }
    int wave = tid >> 6, lane = tid & 63;
    if (lane == 0) { sc[wave] = c; sm[wave] = smm; sl[wave] = ln; }
    __syncthreads();
    if (tid == 0) {
        pC[blockIdx.x] = sc[0] + sc[1] + sc[2] + sc[3];
        pSM[blockIdx.x] = sm[0] + sm[1] + sm[2] + sm[3];
        pLN[blockIdx.x] = sl[0] + sl[1] + sl[2] + sl[3];
    }
}

// ---------------- final ----------------
__global__ __launch_bounds__(64) void k_final(const float* __restrict__ pC,
                                              const float* __restrict__ pSM,
                                              const float* __restrict__ pLN,
                                              float* __restrict__ out, int nb, float npairs) {
    int tid = threadIdx.x;
    float c = 0.f, m = 0.f, ln = 0.f;
    if (tid < nb) { c = pC[tid]; m = pSM[tid]; ln = pLN[tid]; }
#pragma unroll
    for (int d = 1; d < 64; d <<= 1) {
        c += __shfl_xor(c, d); m += __shfl_xor(m, d); ln += __shfl_xor(ln, d);
    }
    if (tid == 0) {
        out[0] = (c > 0.f) ? ln / c : 0.f;
        out[1] = (c > 0.f) ? m / c : 0.f;
        out[2] = c;
        out[3] = c / npairs;
    }
}

extern "C" void kernel_launch(void* const* d_in, const int* in_sizes, int n_in,
                              void* d_out, int out_size, void* d_ws, size_t ws_size,
                              hipStream_t stream) {
    const float* lat = (const float*)d_in[0];
    const float* abr = (const float*)d_in[1];
    float* out = (float*)d_out;
    int B = in_sizes[1] / 6;  // 8192

    char* ws = (char*)d_ws;
    size_t off = 0;
    __hip_bfloat16* lnbf = (__hip_bfloat16*)(ws + off); off += (size_t)B * 128 * 2;  // 2 MB
    _Float16* abrf = (_Float16*)(ws + off); off += (size_t)B * 16 * 2;               // 256 KB
    float4* slab = (float4*)(ws + off); off += (size_t)16 * B * 16;                  // 2 MB
    int nrb = B / 256;  // 32
    float* pC = (float*)(ws + off); off += (size_t)nrb * 4;
    float* pSM = (float*)(ws + off); off += (size_t)nrb * 4;
    float* pLN = (float*)(ws + off); off += (size_t)nrb * 4;

    k_norm_lat<<<B / 4, 256, 0, stream>>>(lat, lnbf, B);
    k_norm_abr<<<(B + 255) / 256, 256, 0, stream>>>(abr, abrf, B);
    k_sweep<<<dim3(8, B / 128), 256, 65536, stream>>>(lnbf, abrf, slab, B);
    k_rows<<<nrb, 256, 0, stream>>>(slab, pC, pSM, pLN, B);
    k_final<<<1, 64, 0, stream>>>(pC, pSM, pLN, out, nrb, (float)B * (float)(B - 1));
}

// Round 6
// 69.160 us; speedup vs baseline: 2.0180x; 2.0180x over previous
//
#include <hip/hip_runtime.h>
#include <hip/hip_bf16.h>
#include <math.h>

#define SIM_THR 0.8f
// sqrt(2 * log2(e)): folds the x2 temperature and the exp->exp2 conversion into the data
#define LAT_SCALE 1.6986436f
#define LN2 0.6931471805599453f

typedef __attribute__((ext_vector_type(8))) short short8v;   // 8 bf16
typedef __attribute__((ext_vector_type(4))) float f32x4;
typedef __attribute__((ext_vector_type(4))) _Float16 half4v; // 4 f16

__device__ __forceinline__ void glds16(const void* g, void* l) {
    __builtin_amdgcn_global_load_lds(
        (const __attribute__((address_space(1))) void*)g,
        (__attribute__((address_space(3))) void*)l, 16, 0, 0);
}

__device__ __forceinline__ float fexp2(float x) {
#if __has_builtin(__builtin_amdgcn_exp2f)
    return __builtin_amdgcn_exp2f(x);
#else
    return exp2f(x);
#endif
}

// ---------------- kernel 1: L2-normalize latent rows -> bf16 (scaled) ----------------
__global__ __launch_bounds__(256) void k_norm_lat(const float* __restrict__ in,
                                                  __hip_bfloat16* __restrict__ out, int B) {
    int row = blockIdx.x * 4 + (threadIdx.x >> 6);
    int lane = threadIdx.x & 63;
    if (row >= B) return;
    float2 v = reinterpret_cast<const float2*>(in + (size_t)row * 128)[lane];
    float ss = v.x * v.x + v.y * v.y;
#pragma unroll
    for (int m = 1; m < 64; m <<= 1) ss += __shfl_xor(ss, m);
    float sc = LAT_SCALE / fmaxf(sqrtf(ss), 1e-12f);
    __hip_bfloat162 o;
    o.x = __float2bfloat16(v.x * sc);
    o.y = __float2bfloat16(v.y * sc);
    reinterpret_cast<__hip_bfloat162*>(out + (size_t)row * 128)[lane] = o;
}

// ---------------- kernel 2: L2-normalize abr rows -> f16, K padded to 16 ----------------
__global__ __launch_bounds__(256) void k_norm_abr(const float* __restrict__ in,
                                                  _Float16* __restrict__ out, int B) {
    int row = blockIdx.x * 256 + threadIdx.x;
    if (row >= B) return;
    float v[6];
    float ss = 0.f;
#pragma unroll
    for (int d = 0; d < 6; ++d) { v[d] = in[(size_t)row * 6 + d]; ss += v[d] * v[d]; }
    float sc = 1.0f / fmaxf(sqrtf(ss), 1e-12f);
#pragma unroll
    for (int d = 0; d < 6; ++d) out[(size_t)row * 16 + d] = (_Float16)(v[d] * sc);
#pragma unroll
    for (int d = 6; d < 16; ++d) out[(size_t)row * 16 + d] = (_Float16)0.f;
}

// ---------------- merged epilogue: abr MFMA + fused per-element stats ----------------
template <bool DIAG>
__device__ __forceinline__ void epilogue(const half4v (&aa)[4], const half4v (&bb)[4],
                                         const f32x4 (&acc)[4][4],
                                         float (&esum_r)[4][4], float (&sumd_r)[4][4],
                                         float (&cnt_r)[4][4], float (&sumsim_r)[4][4],
                                         int lr, int lg, int wr, int wc) {
#pragma unroll
    for (int m = 0; m < 4; ++m) {
#pragma unroll
        for (int n = 0; n < 4; ++n) {
            f32x4 aacc = __builtin_amdgcn_mfma_f32_16x16x16f16(
                aa[m], bb[n], (f32x4){0.f, 0.f, 0.f, 0.f}, 0, 0, 0);
#pragma unroll
            for (int r = 0; r < 4; ++r) {
                float d = acc[m][n][r];       // = s_ij * log2(e)
                float sim = aacc[r];
                float e = fexp2(d);
                bool pred = sim > SIM_THR;
                if (DIAG) {
                    bool dg = (wr * 64 + m * 16 + lg * 4 + r) == (wc * 64 + n * 16 + lr);
                    if (dg) { e = 0.f; pred = false; }
                }
                float p = pred ? 1.f : 0.f;
                esum_r[m][r] += e;
                cnt_r[m][r] += p;
                sumsim_r[m][r] = fmaf(p, sim, sumsim_r[m][r]);
                sumd_r[m][r] = fmaf(p, d, sumd_r[m][r]);
            }
        }
    }
}

// ---------------- fused sweep ----------------
// Block (jc, bi): rows [bi*128,+128), sweeps 8 j-tiles of 128. Per row accumulates
// (esum, sum_d_pos, cnt, sum_sim); one float4 slab write per (row, wc). No atomics.
__global__ __launch_bounds__(256, 2) void k_sweep(
    const __hip_bfloat16* __restrict__ lnbf,
    const _Float16* __restrict__ abrf,
    float4* __restrict__ slab, int B)
{
    extern __shared__ char lds[];
    __hip_bfloat16* Alat = (__hip_bfloat16*)lds;            // 32 KB
    __hip_bfloat16* Blat = (__hip_bfloat16*)(lds + 32768);  // 32 KB

    int jc = blockIdx.x, bi = blockIdx.y;
    int i0 = bi * 128;
    int tid = threadIdx.x;
    int w = tid >> 6, l = tid & 63;
    int lr = l & 15, lg = l >> 4;
    int wr = w >> 1, wc = w & 1;
    int lrow = l >> 4, lch = l & 15;

    // ---- prologue: stage A panel + B panel (tile 0); XOR-swizzled source ----
    {
        int j0 = jc * 1024;
#pragma unroll
        for (int c = 0; c < 8; ++c) {
            int rbase = w * 32 + c * 4;
            int row = rbase + lrow;
            int sch = lch ^ (row & 7);
            glds16(lnbf + (size_t)(i0 + row) * 128 + sch * 8, Alat + rbase * 128);
            glds16(lnbf + (size_t)(j0 + row) * 128 + sch * 8, Blat + rbase * 128);
        }
    }

    // ---- abr A fragments direct from global (L2-resident) ----
    half4v aa[4];
#pragma unroll
    for (int m = 0; m < 4; ++m)
        aa[m] = *reinterpret_cast<const half4v*>(
            abrf + (size_t)(i0 + wr * 64 + m * 16 + lr) * 16 + lg * 4);

    __syncthreads();

    float esum_r[4][4] = {{0.f}}, sumd_r[4][4] = {{0.f}};
    float cnt_r[4][4] = {{0.f}}, sumsim_r[4][4] = {{0.f}};

#pragma unroll 1
    for (int t = 0; t < 8; ++t) {
        int jt = jc * 8 + t;
        bool dtile = (jt == bi);

        // abr B fragments direct from global
        half4v bb[4];
#pragma unroll
        for (int n = 0; n < 4; ++n)
            bb[n] = *reinterpret_cast<const half4v*>(
                abrf + (size_t)(jt * 128 + wc * 64 + n * 16 + lr) * 16 + lg * 4);

        // ---- latent MFMA (A and B fragments from LDS each tile; no reg hoist) ----
        f32x4 acc[4][4];
#pragma unroll
        for (int m = 0; m < 4; ++m)
#pragma unroll
            for (int n = 0; n < 4; ++n) acc[m][n] = (f32x4){0.f, 0.f, 0.f, 0.f};
#pragma unroll
        for (int kk = 0; kk < 4; ++kk) {
            int ch = (kk * 4 + lg) ^ (lr & 7);
            short8v a[4], b[4];
#pragma unroll
            for (int m = 0; m < 4; ++m)
                a[m] = *reinterpret_cast<const short8v*>(
                    Alat + (wr * 64 + m * 16 + lr) * 128 + ch * 8);
#pragma unroll
            for (int n = 0; n < 4; ++n)
                b[n] = *reinterpret_cast<const short8v*>(
                    Blat + (wc * 64 + n * 16 + lr) * 128 + ch * 8);
#pragma unroll
            for (int m = 0; m < 4; ++m)
#pragma unroll
                for (int n = 0; n < 4; ++n)
                    acc[m][n] = __builtin_amdgcn_mfma_f32_16x16x32_bf16(a[m], b[n], acc[m][n], 0, 0, 0);
        }
        __syncthreads();   // all Blat frag reads done -> reusable

        // ---- issue next B staging; flight hidden under epilogue ----
        if (t < 7) {
            int j0n = (jt + 1) * 128;
#pragma unroll
            for (int c = 0; c < 8; ++c) {
                int rbase = w * 32 + c * 4;
                int row = rbase + lrow;
                int sch = lch ^ (row & 7);
                glds16(lnbf + (size_t)(j0n + row) * 128 + sch * 8, Blat + rbase * 128);
            }
        }

        // ---- merged epilogue (registers only) ----
        if (dtile)
            epilogue<true>(aa, bb, acc, esum_r, sumd_r, cnt_r, sumsim_r, lr, lg, wr, wc);
        else
            epilogue<false>(aa, bb, acc, esum_r, sumd_r, cnt_r, sumsim_r, lr, lg, wr, wc);

        if (t < 7) __syncthreads();   // vmcnt drained -> next B ready
    }

    // ---- reduce over the 16 column-lanes and store one float4 per row ----
#pragma unroll
    for (int m = 0; m < 4; ++m)
#pragma unroll
        for (int r = 0; r < 4; ++r) {
            float a0 = esum_r[m][r], a1 = sumd_r[m][r], a2 = cnt_r[m][r], a3 = sumsim_r[m][r];
#pragma unroll
            for (int d2 = 1; d2 < 16; d2 <<= 1) {
                a0 += __shfl_xor(a0, d2);
                a1 += __shfl_xor(a1, d2);
                a2 += __shfl_xor(a2, d2);
                a3 += __shfl_xor(a3, d2);
            }
            if (lr == 0) {
                int row_g = i0 + wr * 64 + m * 16 + lg * 4 + r;
                slab[(size_t)(jc * 2 + wc) * B + row_g] = make_float4(a0, a1, a2, a3);
            }
        }
}

// ---------------- per-row finalize + block partials ----------------
__global__ __launch_bounds__(256) void k_rows(const float4* __restrict__ slab,
                                              float* __restrict__ pC, float* __restrict__ pSM,
                                              float* __restrict__ pLN, int B) {
    __shared__ float sc[4], sm[4], sl[4];
    int tid = threadIdx.x;
    int i = blockIdx.x * 256 + tid;
    float S = 0.f, sd = 0.f, c = 0.f, smm = 0.f;
#pragma unroll
    for (int k = 0; k < 16; ++k) {
        float4 v = slab[(size_t)k * B + i];
        S += v.x; sd += v.y; c += v.z; smm += v.w;
    }
    // loss row term: c*log(S) - sum_pos s;  sd holds sum_pos (s*log2e) -> *ln2
    float ln = (c > 0.f) ? c * logf(S) - LN2 * sd : 0.f;
#pragma unroll
    for (int d = 1; d < 64; d <<= 1) {
        c += __shfl_xor(c, d); smm += __shfl_xor(smm, d); ln += __shfl_xor(ln, d);
    }
    int wave = tid >> 6, lane = tid & 63;
    if (lane == 0) { sc[wave] = c; sm[wave] = smm; sl[wave] = ln; }
    __syncthreads();
    if (tid == 0) {
        pC[blockIdx.x] = sc[0] + sc[1] + sc[2] + sc[3];
        pSM[blockIdx.x] = sm[0] + sm[1] + sm[2] + sm[3];
        pLN[blockIdx.x] = sl[0] + sl[1] + sl[2] + sl[3];
    }
}

// ---------------- final ----------------
__global__ __launch_bounds__(64) void k_final(const float* __restrict__ pC,
                                              const float* __restrict__ pSM,
                                              const float* __restrict__ pLN,
                                              float* __restrict__ out, int nb, float npairs) {
    int tid = threadIdx.x;
    float c = 0.f, m = 0.f, ln = 0.f;
    if (tid < nb) { c = pC[tid]; m = pSM[tid]; ln = pLN[tid]; }
#pragma unroll
    for (int d = 1; d < 64; d <<= 1) {
        c += __shfl_xor(c, d); m += __shfl_xor(m, d); ln += __shfl_xor(ln, d);
    }
    if (tid == 0) {
        out[0] = (c > 0.f) ? ln / c : 0.f;
        out[1] = (c > 0.f) ? m / c : 0.f;
        out[2] = c;
        out[3] = c / npairs;
    }
}

extern "C" void kernel_launch(void* const* d_in, const int* in_sizes, int n_in,
                              void* d_out, int out_size, void* d_ws, size_t ws_size,
                              hipStream_t stream) {
    const float* lat = (const float*)d_in[0];
    const float* abr = (const float*)d_in[1];
    float* out = (float*)d_out;
    int B = in_sizes[1] / 6;  // 8192

    char* ws = (char*)d_ws;
    size_t off = 0;
    __hip_bfloat16* lnbf = (__hip_bfloat16*)(ws + off); off += (size_t)B * 128 * 2;  // 2 MB
    _Float16* abrf = (_Float16*)(ws + off); off += (size_t)B * 16 * 2;               // 256 KB
    float4* slab = (float4*)(ws + off); off += (size_t)16 * B * 16;                  // 2 MB
    int nrb = B / 256;  // 32
    float* pC = (float*)(ws + off); off += (size_t)nrb * 4;
    float* pSM = (float*)(ws + off); off += (size_t)nrb * 4;
    float* pLN = (float*)(ws + off); off += (size_t)nrb * 4;

    k_norm_lat<<<B / 4, 256, 0, stream>>>(lat, lnbf, B);
    k_norm_abr<<<(B + 255) / 256, 256, 0, stream>>>(abr, abrf, B);
    k_sweep<<<dim3(8, B / 128), 256, 65536, stream>>>(lnbf, abrf, slab, B);
    k_rows<<<nrb, 256, 0, stream>>>(slab, pC, pSM, pLN, B);
    k_final<<<1, 64, 0, stream>>>(pC, pSM, pLN, out, nrb, (float)B * (float)(B - 1));
}